// Round 5
// baseline (85.503 us; speedup 1.0000x reference)
//
#include <hip/hip_runtime.h>
#include <hip/hip_bf16.h>
#include <math.h>

#define NEG 0.1f
#define EPSV 1e-8f

constexpr int D  = 1024;
constexpr int BK = 64;        // k per step (8 slots of 8 bf16)
constexpr int NK = D / BK;    // 16
constexpr int BN = 128;

typedef __bf16 bf16x8 __attribute__((ext_vector_type(8)));
typedef __bf16 bf16x4 __attribute__((ext_vector_type(4)));
typedef float  f32x4  __attribute__((ext_vector_type(4)));

__device__ __forceinline__ bf16x8 cvt8(float4 a, float4 b) {
    bf16x8 r;
    r[0] = (__bf16)a.x; r[1] = (__bf16)a.y; r[2] = (__bf16)a.z; r[3] = (__bf16)a.w;
    r[4] = (__bf16)b.x; r[5] = (__bf16)b.y; r[6] = (__bf16)b.z; r[7] = (__bf16)b.w;
    return r;
}

// async global->LDS, 16B per lane; LDS dest is wave-uniform base + lane*16
__device__ __forceinline__ void gld_lds16(const __bf16* g, __bf16* l) {
    __builtin_amdgcn_global_load_lds(
        (__attribute__((address_space(1))) void*)(size_t)(const void*)g,
        (__attribute__((address_space(3))) void*)l,
        16, 0, 0);
}

// ---------- fused conversion kernel ----------
// blocks [0,4096):   W (2x 1024x128 slot-tasks) then img (128*48 rows x 128 slots,
//                    rows padded to 48/batch with zeros), both bf16 slot-swizzled.
// blocks [4096,4608): cap -> bf16 swizzled + per-(c,quarter) masked partial sums.
__global__ __launch_bounds__(256)
void convert_all(const float* __restrict__ Wvt, const float* __restrict__ Wvi,
                 const float* __restrict__ img, const float* __restrict__ cap,
                 const int* __restrict__ lens,
                 __bf16* __restrict__ wtb, __bf16* __restrict__ wib,
                 __bf16* __restrict__ imgb, __bf16* __restrict__ capb,
                 float* __restrict__ cappart)
{
    const int bid = blockIdx.x;
    if (bid < 4096) {
        int g = bid * 256 + threadIdx.x;
        if (g < 262144) {
            // ---- W path: slot s of dst holds orig slot s^(e&7) ----
            const float* src = (g < 131072) ? Wvt : Wvi;
            __bf16*      dst = (g < 131072) ? wtb : wib;
            g &= 131071;
            const int e  = g >> 7;
            const int sl = g & 127;
            const int c  = sl >> 3, si = sl & 7;
            const int ss = (c << 3) | (si ^ (e & 7));
            const float* p = src + (size_t)e * D + ss * 8;
            *(bf16x8*)(dst + (size_t)e * D + sl * 8) =
                cvt8(*(const float4*)p, *(const float4*)(p + 4));
        } else {
            // ---- img path: [128][36] -> [128][48] rows, swizzle key t&7 ----
            const int gg = g - 262144;            // < 786432
            const int Rd = gg >> 7, sl = gg & 127;
            const int c  = Rd / 48, t = Rd - c * 48;
            bf16x8 w;
            if (t < 36) {
                const int ch = sl >> 3, u = sl & 7;
                const int s2 = (ch << 3) | (u ^ (t & 7));
                const float* p = img + (size_t)(c * 36 + t) * D + s2 * 8;
                w = cvt8(*(const float4*)p, *(const float4*)(p + 4));
            } else {
                #pragma unroll
                for (int j = 0; j < 8; ++j) w[j] = (__bf16)0.f;
            }
            *(bf16x8*)(imgb + (size_t)Rd * D + sl * 8) = w;
        }
    } else {
        // ---- cap path: (c, quarter) block converts 16 rows + partial sum ----
        const int cb2 = bid - 4096;               // 0..511
        const int c = cb2 >> 2, q = cb2 & 3;
        const int tid = threadIdx.x;
        const int col = tid * 4;
        const int cb = col & ~63, u = (col >> 3) & 7, lo = col & 7;
        const int len = lens[c];
        const float* src = cap + (size_t)c * 64 * D + col;
        __bf16* drow = capb + (size_t)c * 64 * D;
        float4 acc = make_float4(0.f, 0.f, 0.f, 0.f);
        #pragma unroll
        for (int tt = 0; tt < 16; ++tt) {
            const int t = q * 16 + tt;
            float4 v = *(const float4*)(src + (size_t)t * D);
            if (t < len) { acc.x += v.x; acc.y += v.y; acc.z += v.z; acc.w += v.w; }
            bf16x4 w;
            w[0] = (__bf16)v.x; w[1] = (__bf16)v.y;
            w[2] = (__bf16)v.z; w[3] = (__bf16)v.w;
            *(bf16x4*)(drow + (size_t)t * D + cb + ((u ^ (t & 7)) << 3) + lo) = w;
        }
        *(float4*)(cappart + ((size_t)q * 128 + c) * D + col) = acc;
    }
}

// cap_vec[c] = l2norm( (sum_q part[q][c]) / len )
__global__ __launch_bounds__(256)
void capfin(const float* __restrict__ cappart, const int* __restrict__ lens,
            float* __restrict__ capv)
{
    const int c = blockIdx.x, tid = threadIdx.x;
    const int col = tid * 4;
    float4 acc = make_float4(0.f, 0.f, 0.f, 0.f);
    #pragma unroll
    for (int q = 0; q < 4; ++q) {
        float4 v = *(const float4*)(cappart + ((size_t)q * 128 + c) * D + col);
        acc.x += v.x; acc.y += v.y; acc.z += v.z; acc.w += v.w;
    }
    const float inv = 1.f / (float)lens[c];
    acc.x *= inv; acc.y *= inv; acc.z *= inv; acc.w *= inv;
    float ss = acc.x * acc.x + acc.y * acc.y + acc.z * acc.z + acc.w * acc.w;
    #pragma unroll
    for (int o = 32; o > 0; o >>= 1) ss += __shfl_xor(ss, o, 64);
    __shared__ float wsum[4];
    if ((tid & 63) == 0) wsum[tid >> 6] = ss;
    __syncthreads();
    const float total = wsum[0] + wsum[1] + wsum[2] + wsum[3];
    const float r = 1.f / (sqrtf(total) + EPSV);
    float4 o4 = make_float4(acc.x * r, acc.y * r, acc.z * r, acc.w * r);
    *(float4*)(capv + (size_t)c * D + col) = o4;
}

// ---------- GEMM body: all-async staging, counted vmcnt, XCD batch-partition ----
template<int RPAD, int ROWS>
__device__ __forceinline__ void vsum_body(
    const __bf16* __restrict__ Acvt, const __bf16* __restrict__ Wsw,
    const float* __restrict__ bias, const int* __restrict__ lens,
    float scale, float* __restrict__ out, int wg, __bf16* sm)
{
    constexpr int G      = 2;
    constexpr int BM     = G * RPAD;        // 128 (cap) / 96 (img)
    constexpr int M_REP  = BM / 16;         // 8 / 6
    constexpr int N_REP  = 2;
    constexpr int ACALLS = BM / 32;         // per-wave A gload calls (4 / 3)
    constexpr int LCNT   = ACALLS + 4;      // per-wave vmem instrs per k-step

    __bf16* A0 = sm;
    __bf16* A1 = A0 + BM * BK;
    __bf16* B0 = A1 + BM * BK;
    __bf16* B1 = B0 + BN * BK;

    const int tid  = threadIdx.x;
    const int wid  = tid >> 6;
    const int lane = tid & 63;
    const int r16  = lane & 15;
    const int kg   = lane >> 4;

    // XCD-aware: each XCD owns 16 batches x all 8 e-columns (L2-resident set)
    const int xcd = wg & 7;
    const int idx = wg >> 3;                // 0..63
    const int jj  = idx & 7;                // e-column
    const int y   = xcd * 8 + (idx >> 3);   // batch-group 0..63
    const int e0  = jj * BN;
    const int b0  = y * G;

    const __bf16* Ab = Acvt + (size_t)b0 * RPAD * D;

    f32x4 acc[M_REP][N_REP];
    #pragma unroll
    for (int mi = 0; mi < M_REP; ++mi)
        #pragma unroll
        for (int ni = 0; ni < N_REP; ++ni)
            acc[mi][ni] = (f32x4){0.f, 0.f, 0.f, 0.f};

    auto issueA = [&](int ks, __bf16* dst) {
        #pragma unroll
        for (int cc = 0; cc < ACALLS; ++cc) {
            const int rbase = (wid * ACALLS + cc) * 8;
            const int r = rbase + (lane >> 3);
            gld_lds16(Ab + (size_t)r * D + ks * BK + (lane & 7) * 8,
                      dst + rbase * BK);
        }
    };
    auto issueB = [&](int ks, __bf16* dst) {
        #pragma unroll
        for (int cc = 0; cc < 4; ++cc) {
            const int rbase = (wid * 4 + cc) * 8;
            const int r = rbase + (lane >> 3);
            gld_lds16(Wsw + (size_t)(e0 + r) * D + ks * BK + (lane & 7) * 8,
                      dst + rbase * BK);
        }
    };
    auto compute = [&](__bf16* Ac, __bf16* Bc) {
        #pragma unroll
        for (int ksub = 0; ksub < 2; ++ksub) {
            bf16x8 af[M_REP], bfr[N_REP];
            #pragma unroll
            for (int mi = 0; mi < M_REP; ++mi) {
                const int row = mi * 16 + r16;
                af[mi] = *(bf16x8*)&Ac[row * BK + (((ksub * 4 + kg) ^ (row & 7)) << 3)];
            }
            #pragma unroll
            for (int ni = 0; ni < N_REP; ++ni) {
                const int row = wid * 32 + ni * 16 + r16;
                bfr[ni] = *(bf16x8*)&Bc[row * BK + (((ksub * 4 + kg) ^ (row & 7)) << 3)];
            }
            #pragma unroll
            for (int mi = 0; mi < M_REP; ++mi)
                #pragma unroll
                for (int ni = 0; ni < N_REP; ++ni)
                    acc[mi][ni] = __builtin_amdgcn_mfma_f32_16x16x32_bf16(
                        af[mi], bfr[ni], acc[mi][ni], 0, 0, 0);
        }
    };
    auto step = [&](int ks, __bf16* Ac, __bf16* Bc, __bf16* An, __bf16* Bn) {
        if (ks + 1 < NK) {
            issueA(ks + 1, An); issueB(ks + 1, Bn);
            // wait for CURRENT buf's loads; keep next step's LCNT in flight
            asm volatile("s_waitcnt vmcnt(%0)" :: "n"(LCNT) : "memory");
        } else {
            asm volatile("s_waitcnt vmcnt(0)" ::: "memory");
        }
        __builtin_amdgcn_s_barrier();             // cur buf visible to all waves
        __builtin_amdgcn_sched_barrier(0);
        compute(Ac, Bc);
        __builtin_amdgcn_sched_barrier(0);
        __builtin_amdgcn_s_barrier();             // reads done before overwrite
    };

    issueA(0, A0); issueB(0, B0);
    for (int ks = 0; ks < NK; ks += 2) {
        step(ks,     A0, B0, A1, B1);
        step(ks + 1, A1, B1, A0, B0);
    }

    // ---- epilogue: bias + leaky + per-group mask + reduce over rows ----
    int lb0 = ROWS, lb1 = ROWS;
    if (lens) {
        const int l0 = lens[b0], l1 = lens[b0 + 1];
        lb0 = l0 < ROWS ? l0 : ROWS;
        lb1 = l1 < ROWS ? l1 : ROWS;
    }
    float bv[N_REP];
    #pragma unroll
    for (int ni = 0; ni < N_REP; ++ni) bv[ni] = bias[e0 + wid * 32 + ni * 16 + r16];

    float part[2][N_REP];
    part[0][0] = part[0][1] = part[1][0] = part[1][1] = 0.f;

    #pragma unroll
    for (int mi = 0; mi < M_REP; ++mi) {
        #pragma unroll
        for (int j = 0; j < 4; ++j) {
            const int row = mi * 16 + kg * 4 + j;
            const int g   = row >= RPAD;
            const int t   = row - (g ? RPAD : 0);
            const int lb  = g ? lb1 : lb0;
            if (t < lb) {
                #pragma unroll
                for (int ni = 0; ni < N_REP; ++ni) {
                    float v = acc[mi][ni][j] + bv[ni];
                    v = v > 0.f ? v : NEG * v;     // leaky before mask (ref order)
                    if (g) part[1][ni] += v; else part[0][ni] += v;
                }
            }
        }
    }
    #pragma unroll
    for (int g = 0; g < 2; ++g)
        #pragma unroll
        for (int ni = 0; ni < N_REP; ++ni) {
            part[g][ni] += __shfl_xor(part[g][ni], 16, 64);
            part[g][ni] += __shfl_xor(part[g][ni], 32, 64);
        }
    const float v = (kg == 0) ? part[0][0] : (kg == 1) ? part[0][1]
                  : (kg == 2) ? part[1][0] : part[1][1];
    const int gg = kg >> 1, nn = kg & 1;
    out[(size_t)(b0 + gg) * D + e0 + wid * 32 + nn * 16 + r16] = scale * v;
}

// union launch: blocks [0,512) cap-GEMM, [512,1024) img-GEMM (backfills tail)
__global__ __launch_bounds__(256)
void vsum_union(const __bf16* __restrict__ capb, const __bf16* __restrict__ wtb,
                const float* __restrict__ bvt,
                const __bf16* __restrict__ imgb, const __bf16* __restrict__ wib,
                const float* __restrict__ bvi,
                const int* __restrict__ lens, float scale,
                float* __restrict__ ctxbar, float* __restrict__ vbar)
{
    extern __shared__ __bf16 sm[];
    if (blockIdx.x < 512)
        vsum_body<64, 64>(capb, wtb, bvt, lens, scale, ctxbar, blockIdx.x, sm);
    else
        vsum_body<48, 36>(imgb, wib, bvi, nullptr, scale, vbar, blockIdx.x - 512, sm);
}

// ---------- fallback (proven R3 path, used if ws too small) ----------
__global__ __launch_bounds__(256)
void convert_w(const float* __restrict__ W0, const float* __restrict__ W1,
               __bf16* __restrict__ O0, __bf16* __restrict__ O1)
{
    int g = blockIdx.x * 256 + threadIdx.x;
    const float* src = (g < 131072) ? W0 : W1;
    __bf16*      dst = (g < 131072) ? O0 : O1;
    g &= 131071;
    const int e  = g >> 7;
    const int sl = g & 127;
    const int c  = sl >> 3, si = sl & 7;
    const int ss = (c << 3) | (si ^ (e & 7));
    const float* p = src + (size_t)e * D + ss * 8;
    *(bf16x8*)(dst + (size_t)e * D + sl * 8) =
        cvt8(*(const float4*)p, *(const float4*)(p + 4));
}

template<int BM, int ROWS>
__global__ __launch_bounds__(256)
void vsum_mfma_rs(const float* __restrict__ A,
                  const __bf16* __restrict__ Wsw,
                  const float* __restrict__ bias,
                  const int*   __restrict__ lens,
                  float scale,
                  float* __restrict__ out)
{
    constexpr int G      = 2;
    constexpr int M_REP  = BM / 16;
    constexpr int N_REP  = 2;
    constexpr int ATASK  = BM * 4;

    __shared__ __bf16 Asm[2][BM * BK];
    __shared__ __bf16 Bsm[2][BN * BK];

    const int tid  = threadIdx.x;
    const int wid  = tid >> 6;
    const int lane = tid & 63;
    const int r16  = lane & 15;
    const int kg   = lane >> 4;
    const int e0   = blockIdx.x * BN;
    const int b0   = blockIdx.y * G;

    const float* Ab = A + (size_t)b0 * ROWS * D;

    int arow[2], aseg[2]; bool alive[2];
    const float* aptr[2];
    #pragma unroll
    for (int p = 0; p < 2; ++p) {
        const int task = tid + p * 256;
        const bool act = task < ATASK;
        const int r  = act ? (task % BM) : 0;
        const int ks = act ? (task / BM) : 0;
        arow[p] = r; aseg[p] = ks;
        alive[p] = act && (r < G * ROWS);
        aptr[p] = Ab + (size_t)r * D + ks * 16;
    }

    float4 ra[2][4];
    f32x4 acc[M_REP][N_REP];
    #pragma unroll
    for (int mi = 0; mi < M_REP; ++mi)
        #pragma unroll
        for (int ni = 0; ni < N_REP; ++ni)
            acc[mi][ni] = (f32x4){0.f, 0.f, 0.f, 0.f};

    auto loadA = [&](int ks) {
        #pragma unroll
        for (int p = 0; p < 2; ++p)
            if (alive[p]) {
                const float* q = aptr[p] + ks * BK;
                ra[p][0] = *(const float4*)(q + 0);
                ra[p][1] = *(const float4*)(q + 4);
                ra[p][2] = *(const float4*)(q + 8);
                ra[p][3] = *(const float4*)(q + 12);
            }
    };
    auto stageA = [&](int buf) {
        #pragma unroll
        for (int p = 0; p < 2; ++p)
            if (alive[p]) {
                bf16x8 w0 = cvt8(ra[p][0], ra[p][1]);
                bf16x8 w1 = cvt8(ra[p][2], ra[p][3]);
                const int base = arow[p] * BK, sw = arow[p] & 7;
                *(bf16x8*)&Asm[buf][base + (((aseg[p] * 2 + 0) ^ sw) << 3)] = w0;
                *(bf16x8*)&Asm[buf][base + (((aseg[p] * 2 + 1) ^ sw) << 3)] = w1;
            }
    };
    auto issueB = [&](int ks, int buf) {
        #pragma unroll
        for (int c = 0; c < 4; ++c) {
            const int rbase = (wid * 4 + c) * 8;
            const int r = rbase + (lane >> 3);
            gld_lds16(Wsw + (size_t)(e0 + r) * D + ks * BK + (lane & 7) * 8,
                      &Bsm[buf][rbase * BK]);
        }
    };
    auto compute = [&](int buf) {
        #pragma unroll
        for (int ksub = 0; ksub < 2; ++ksub) {
            bf16x8 af[M_REP], bfr[N_REP];
            #pragma unroll
            for (int mi = 0; mi < M_REP; ++mi) {
                const int row = mi * 16 + r16;
                af[mi] = *(bf16x8*)&Asm[buf][row * BK + (((ksub * 4 + kg) ^ (row & 7)) << 3)];
            }
            #pragma unroll
            for (int ni = 0; ni < N_REP; ++ni) {
                const int row = wid * 32 + ni * 16 + r16;
                bfr[ni] = *(bf16x8*)&Bsm[buf][row * BK + (((ksub * 4 + kg) ^ (row & 7)) << 3)];
            }
            #pragma unroll
            for (int mi = 0; mi < M_REP; ++mi)
                #pragma unroll
                for (int ni = 0; ni < N_REP; ++ni)
                    acc[mi][ni] = __builtin_amdgcn_mfma_f32_16x16x32_bf16(
                        af[mi], bfr[ni], acc[mi][ni], 0, 0, 0);
        }
    };

    issueB(0, 0);
    loadA(0);
    stageA(0);
    __syncthreads();

    int cur = 0;
    #pragma unroll 2
    for (int ks = 0; ks < NK; ++ks) {
        const bool more = (ks + 1) < NK;
        if (more) { issueB(ks + 1, cur ^ 1); loadA(ks + 1); }
        compute(cur);
        if (more) stageA(cur ^ 1);
        __syncthreads();
        cur ^= 1;
    }

    int lb0 = ROWS, lb1 = ROWS;
    if (lens) {
        const int l0 = lens[b0], l1 = lens[b0 + 1];
        lb0 = l0 < ROWS ? l0 : ROWS;
        lb1 = l1 < ROWS ? l1 : ROWS;
    }
    float bv[N_REP];
    #pragma unroll
    for (int ni = 0; ni < N_REP; ++ni) bv[ni] = bias[e0 + wid * 32 + ni * 16 + r16];
    float part[2][N_REP];
    part[0][0] = part[0][1] = part[1][0] = part[1][1] = 0.f;
    #pragma unroll
    for (int mi = 0; mi < M_REP; ++mi) {
        #pragma unroll
        for (int j = 0; j < 4; ++j) {
            const int row = mi * 16 + kg * 4 + j;
            if (row < 2 * ROWS) {
                const int g  = row >= ROWS;
                const int t  = row - (g ? ROWS : 0);
                const int lb = g ? lb1 : lb0;
                if (t < lb) {
                    #pragma unroll
                    for (int ni = 0; ni < N_REP; ++ni) {
                        float v = acc[mi][ni][j] + bv[ni];
                        v = v > 0.f ? v : NEG * v;
                        if (g) part[1][ni] += v; else part[0][ni] += v;
                    }
                }
            }
        }
    }
    #pragma unroll
    for (int g = 0; g < 2; ++g)
        #pragma unroll
        for (int ni = 0; ni < N_REP; ++ni) {
            part[g][ni] += __shfl_xor(part[g][ni], 16, 64);
            part[g][ni] += __shfl_xor(part[g][ni], 32, 64);
        }
    const float v = (kg == 0) ? part[0][0] : (kg == 1) ? part[0][1]
                  : (kg == 2) ? part[1][0] : part[1][1];
    const int gg = kg >> 1, nn = kg & 1;
    out[(size_t)(b0 + gg) * D + e0 + wid * 32 + nn * 16 + r16] = scale * v;
}

__global__ __launch_bounds__(256)
void capvec_kernel(const float* __restrict__ cap, const int* __restrict__ lens,
                   float* __restrict__ capv)
{
    const int c = blockIdx.x, tid = threadIdx.x;
    const int len = lens[c];
    const float* base = cap + (size_t)c * 64 * D + tid * 4;
    float4 acc = make_float4(0.f, 0.f, 0.f, 0.f);
    for (int t = 0; t < len; ++t) {
        float4 v = *(const float4*)(base + (size_t)t * D);
        acc.x += v.x; acc.y += v.y; acc.z += v.z; acc.w += v.w;
    }
    const float inv = 1.f / (float)len;
    acc.x *= inv; acc.y *= inv; acc.z *= inv; acc.w *= inv;
    float ss = acc.x * acc.x + acc.y * acc.y + acc.z * acc.z + acc.w * acc.w;
    #pragma unroll
    for (int o = 32; o > 0; o >>= 1) ss += __shfl_xor(ss, o, 64);
    __shared__ float wsum[4];
    if ((tid & 63) == 0) wsum[tid >> 6] = ss;
    __syncthreads();
    const float total = wsum[0] + wsum[1] + wsum[2] + wsum[3];
    const float r = 1.f / (sqrtf(total) + EPSV);
    float4 o4 = make_float4(acc.x * r, acc.y * r, acc.z * r, acc.w * r);
    *(float4*)(capv + (size_t)c * D + tid * 4) = o4;
}

// sims[i,c] = (g*<ctx_c,cap_c> + <vb_i,cap_c>) /
//             (sqrt(g^2*|ctx_c|^2 + 2g*<ctx_c,vb_i> + |vb_i|^2) + eps)
__global__ __launch_bounds__(256)
void sims_kernel(const float* __restrict__ ctxbar, const float* __restrict__ vbar,
                 const float* __restrict__ capv, const float* __restrict__ gptr,
                 float* __restrict__ out)
{
    constexpr int KC3 = 256;
    __shared__ float Cx[16][KC3 + 4];
    __shared__ float Vb[16][KC3 + 4];
    __shared__ float Cp[16][KC3 + 4];
    const int tid = threadIdx.x;
    const int tx = tid & 15;
    const int ty = tid >> 4;
    const int c0 = blockIdx.x * 16, i0 = blockIdx.y * 16;

    float s1 = 0.f, s2 = 0.f, s3 = 0.f, s4 = 0.f, s5 = 0.f;
    for (int k0 = 0; k0 < D; k0 += KC3) {
        for (int idx = tid; idx < 16 * (KC3 / 4); idx += 256) {
            int row = idx >> 6;
            int k4  = (idx & 63) << 2;
            *(float4*)&Cx[row][k4] = *(const float4*)(ctxbar + (size_t)(c0 + row) * D + k0 + k4);
            *(float4*)&Vb[row][k4] = *(const float4*)(vbar   + (size_t)(i0 + row) * D + k0 + k4);
            *(float4*)&Cp[row][k4] = *(const float4*)(capv   + (size_t)(c0 + row) * D + k0 + k4);
        }
        __syncthreads();
        #pragma unroll 8
        for (int k4 = 0; k4 < KC3 / 4; ++k4) {
            float4 xc = *(const float4*)&Cx[tx][k4 * 4];
            float4 xv = *(const float4*)&Vb[ty][k4 * 4];
            float4 xp = *(const float4*)&Cp[tx][k4 * 4];
            s1 += xc.x * xv.x + xc.y * xv.y + xc.z * xv.z + xc.w * xv.w;
            s2 += xv.x * xp.x + xv.y * xp.y + xv.z * xp.z + xv.w * xp.w;
            s3 += xc.x * xp.x + xc.y * xp.y + xc.z * xp.z + xc.w * xp.w;
            s4 += xc.x * xc.x + xc.y * xc.y + xc.z * xc.z + xc.w * xc.w;
            s5 += xv.x * xv.x + xv.y * xv.y + xv.z * xv.z + xv.w * xv.w;
        }
        __syncthreads();
    }
    const float g = *gptr;
    const float num = g * s3 + s2;
    const float den = sqrtf(g * g * s4 + 2.f * g * s1 + s5) + EPSV;
    out[(size_t)(i0 + ty) * 128 + (c0 + tx)] = num / den;
}

extern "C" void kernel_launch(void* const* d_in, const int* in_sizes, int n_in,
                              void* d_out, int out_size, void* d_ws, size_t ws_size,
                              hipStream_t stream)
{
    const float* img  = (const float*)d_in[0];   // [128,36,1024]
    const float* cap  = (const float*)d_in[1];   // [128,64,1024]
    const int*   lens = (const int*)  d_in[2];   // [128]
    const float* Wvi  = (const float*)d_in[7];   // [1024,1024]
    const float* bvi  = (const float*)d_in[8];
    const float* Wvt  = (const float*)d_in[9];   // [1024,1024]
    const float* bvt  = (const float*)d_in[10];
    const float* gamma = (const float*)d_in[11];
    // Wq/bq/Wk/bk/alpha/beta dead: softmax then mean over same axis == 1/R.

    float* out = (float*)d_out;
    const float scale = 1.f / 36.f;      // attn_mean == 1/R exactly
    dim3 blk(256);

    // primary ws: wtb 2M | wib 2M | capb 16M | imgb 12M | ctx/vb/capv 1.5M | cappart 2M
    const size_t NEED = 2097152ull * 2 + 16777216ull + 12582912ull
                      + 3ull * 524288ull + 2097152ull;

    if (ws_size >= NEED) {
        __bf16* wtb  = (__bf16*)d_ws;
        __bf16* wib  = wtb + (size_t)1024 * 1024;
        __bf16* capb = wib + (size_t)1024 * 1024;            // 128*64*1024
        __bf16* imgb = capb + (size_t)128 * 64 * 1024;       // 128*48*1024
        float* ctxbar  = (float*)(imgb + (size_t)128 * 48 * 1024);
        float* vbar    = ctxbar + 128 * 1024;
        float* capv    = vbar   + 128 * 1024;
        float* cappart = capv   + 128 * 1024;                // 4*128*1024

        convert_all<<<dim3(4608), blk, 0, stream>>>(Wvt, Wvi, img, cap, lens,
                                                    wtb, wib, imgb, capb, cappart);
        capfin<<<dim3(128), blk, 0, stream>>>(cappart, lens, capv);
        vsum_union<<<dim3(1024), blk, 65536, stream>>>(capb, wtb, bvt,
                                                       imgb, wib, bvi,
                                                       lens, scale, ctxbar, vbar);
        sims_kernel<<<dim3(8, 8), blk, 0, stream>>>(ctxbar, vbar, capv, gamma, out);
    } else {
        // fallback: R3 path (needs 5.5 MB)
        __bf16* wtb = (__bf16*)d_ws;
        __bf16* wib = wtb + (size_t)1024 * 1024;
        float* ctxbar = (float*)(wib + (size_t)1024 * 1024);
        float* vbar   = ctxbar + 128 * 1024;
        float* capv   = vbar   + 128 * 1024;

        convert_w<<<dim3(1024), blk, 0, stream>>>(Wvt, Wvi, wtb, wib);
        vsum_mfma_rs<128, 64><<<dim3(8, 64), blk, 0, stream>>>(cap, wtb, bvt, lens, scale, ctxbar);
        vsum_mfma_rs< 80, 36><<<dim3(8, 64), blk, 0, stream>>>(img, wib, bvi, nullptr, scale, vbar);
        capvec_kernel<<<dim3(128), blk, 0, stream>>>(cap, lens, capv);
        sims_kernel<<<dim3(8, 8), blk, 0, stream>>>(ctxbar, vbar, capv, gamma, out);
    }
}